// Round 5
// baseline (284.288 us; speedup 1.0000x reference)
//
#include <hip/hip_runtime.h>

// GND_61873298866219 — graph attention distance kernel
// Outputs (concat): attentions [E,4] floats, then f_src [E,4,16] floats.

#define NREP 16  // denom replication factor (contention spreading)

typedef float fvec4 __attribute__((ext_vector_type(4)));  // native vec for nontemporal builtins

static __device__ __forceinline__ void nt_store4(const float4& v, float4* p) {
    fvec4 nv = { v.x, v.y, v.z, v.w };
    __builtin_nontemporal_store(nv, (fvec4*)p);
}

static __device__ __forceinline__ unsigned fmap_ord(float x) {
    // order-preserving float -> uint map (for atomicMin)
    unsigned u = __float_as_uint(x);
    return (u >> 31) ? ~u : (u | 0x80000000u);
}

__global__ void gnd_init(float* __restrict__ denomR, double* __restrict__ gsum,
                         unsigned* __restrict__ gminu, int n)  // n = NREP*N*4
{
    int i = blockIdx.x * blockDim.x + threadIdx.x;
    int stride = gridDim.x * blockDim.x;
    for (int j = i; j < n; j += stride) denomR[j] = 0.0f;
    if (blockIdx.x == 0 && threadIdx.x < 4) {
        gsum[threadIdx.x] = 0.0;
        gminu[threadIdx.x] = 0xFFFFFFFFu;
    }
}

__global__ __launch_bounds__(256) void gnd_pass1(
    const float4* __restrict__ nodes4,     // [N*16] float4 (N nodes x 64 floats)
    const int* __restrict__ trgA,          // [E]
    const int* __restrict__ srcA,          // [E]
    const float4* __restrict__ w_edge4,    // [16]
    const float4* __restrict__ w_dist4,    // [16]
    float4* __restrict__ out_fsrc4,        // [E*16]
    float* __restrict__ ed,                // [E*4]
    double* __restrict__ gsum,             // [4]
    unsigned* __restrict__ gminu,          // [4]
    int E)
{
    const int lane = threadIdx.x & 63;
    const int q = lane & 15;               // float4 index within node (0..15)
    const int h = (lane >> 2) & 3;         // head for this lane's float4
    const float4 wE = w_edge4[q];
    const float4 wD = w_dist4[q];

    double sumAcc = 0.0;
    float  minAcc = 3.4e38f;

    const int gid  = blockIdx.x * blockDim.x + threadIdx.x;
    const int grp0 = gid >> 4;                          // edge-group id
    const int ngrp = (gridDim.x * blockDim.x) >> 4;     // total groups

    for (int base = grp0; base < E; base += 4 * ngrp) {
        int   eA[4], tA[4], sA[4];
        float4 fsA[4], ftA[4];
        #pragma unroll
        for (int k = 0; k < 4; ++k) {
            int e = base + k * ngrp;
            eA[k] = e;
            if (e < E) { tA[k] = trgA[e]; sA[k] = srcA[e]; }
        }
        #pragma unroll
        for (int k = 0; k < 4; ++k) {
            if (eA[k] < E) {
                fsA[k] = nodes4[sA[k] * 16 + q];
                ftA[k] = nodes4[tA[k] * 16 + q];
            }
        }
        #pragma unroll
        for (int k = 0; k < 4; ++k) {
            int e = eA[k];
            if (e >= E) break;
            float4 fs = fsA[k], ft = ftA[k];
            nt_store4(fs, &out_fsrc4[(size_t)e * 16 + q]);
            float ax = (ft.x - fs.x) * wE.x;
            float ay = (ft.y - fs.y) * wE.y;
            float az = (ft.z - fs.z) * wE.z;
            float aw = (ft.w - fs.w) * wE.w;
            float v = ax * ax * wD.x + ay * ay * wD.y + az * az * wD.z + aw * aw * wD.w;
            // reduce the 4 lanes of one head (adjacent lanes, uniform e per group)
            v += __shfl_xor(v, 1);
            v += __shfl_xor(v, 2);
            if ((lane & 3) == 0) {
                __builtin_nontemporal_store(v, &ed[(size_t)e * 4 + h]);
                sumAcc += (double)v;
                minAcc = fminf(minAcc, v);
            }
        }
    }
    // wave-level: combine the 4 contributing 16-lane groups (same h at lane^16, lane^32)
    sumAcc += __shfl_xor(sumAcc, 16);
    sumAcc += __shfl_xor(sumAcc, 32);
    minAcc = fminf(minAcc, __shfl_xor(minAcc, 16));
    minAcc = fminf(minAcc, __shfl_xor(minAcc, 32));

    __shared__ double sSum[4][4];  // [wave][head]
    __shared__ float  sMin[4][4];
    int wv = threadIdx.x >> 6;
    if (lane < 16 && (lane & 3) == 0) {
        sSum[wv][h] = sumAcc;
        sMin[wv][h] = minAcc;
    }
    __syncthreads();
    if (threadIdx.x < 4) {
        int hh = threadIdx.x;
        double s = sSum[0][hh] + sSum[1][hh] + sSum[2][hh] + sSum[3][hh];
        float  m = fminf(fminf(sMin[0][hh], sMin[1][hh]),
                         fminf(sMin[2][hh], sMin[3][hh]));
        atomicAdd(&gsum[hh], s);
        atomicMin(&gminu[hh], fmap_ord(m));
    }
}

__global__ void gnd_finalize(const double* __restrict__ gsum,
                             const unsigned* __restrict__ gminu,
                             float* __restrict__ consts, int E)
{
    if (threadIdx.x == 0 && blockIdx.x == 0) {
        float smax = -3.4e38f;
        for (int hh = 0; hh < 4; ++hh) {
            float mean = (float)(gsum[hh] / (double)E);
            unsigned m = gminu[hh];
            unsigned bits = (m >> 31) ? (m ^ 0x80000000u) : ~m;
            float mn = __uint_as_float(bits);
            float x = mn + mean;
            float lr = (x >= 0.f) ? x : 0.2f * x;
            smax = fmaxf(smax, -lr);
            consts[hh] = mean;
        }
        consts[4] = smax;
    }
}

static __device__ __forceinline__ float lrelu_exp(float x, float smax) {
    float lr = (x >= 0.f) ? x : 0.2f * x;
    return expf(-lr - smax);
}

static __device__ __forceinline__ float head_mean(float m0, float m1, float m2, float m3, int hh) {
    float a = (hh & 1) ? m1 : m0;
    float b = (hh & 1) ? m3 : m2;
    return (hh & 2) ? b : a;
}

// per-(edge,head) mapping: adjacent lanes -> same edge, 4 consecutive denom
// addresses (one 16B sector per edge). Each block accumulates into one of
// NREP denom replicas -> per-line atomic contention / NREP.
__global__ __launch_bounds__(256) void gnd_pass2(
    const float* __restrict__ ed,          // [E*4]
    const int* __restrict__ trgA,
    const float* __restrict__ consts,
    float* __restrict__ denomR,            // [NREP][N*4], pre-zeroed
    int total, int n4)                     // E*4, N*4
{
    const float m0 = consts[0], m1 = consts[1], m2 = consts[2], m3 = consts[3];
    const float smax = consts[4];
    float* myden = denomR + (size_t)(blockIdx.x & (NREP - 1)) * n4;
    int gid = blockIdx.x * blockDim.x + threadIdx.x;
    int stride = gridDim.x * blockDim.x;
    for (int i = gid; i < total; i += stride) {
        int e = i >> 2, hh = i & 3;
        float x = ed[i] + head_mean(m0, m1, m2, m3, hh);
        unsafeAtomicAdd(&myden[trgA[e] * 4 + hh], lrelu_exp(x, smax));
    }
}

__global__ void gnd_collapse(const float4* __restrict__ denomR4,  // [NREP][N]
                             float4* __restrict__ denom4,         // [N]
                             int n)                               // N
{
    int i = blockIdx.x * blockDim.x + threadIdx.x;
    int stride = gridDim.x * blockDim.x;
    for (int j = i; j < n; j += stride) {
        float4 s = denomR4[j];
        #pragma unroll
        for (int r = 1; r < NREP; ++r) {
            float4 t = denomR4[(size_t)r * n + j];
            s.x += t.x; s.y += t.y; s.z += t.z; s.w += t.w;
        }
        denom4[j] = s;
    }
}

__global__ __launch_bounds__(256) void gnd_pass3(
    const float4* __restrict__ ed4,
    const int* __restrict__ trgA,
    const float* __restrict__ consts,
    const float4* __restrict__ denom4,     // [N]
    float4* __restrict__ attOut4,          // [E]
    int E)
{
    const float m0 = consts[0], m1 = consts[1], m2 = consts[2], m3 = consts[3];
    const float smax = consts[4];
    int gid = blockIdx.x * blockDim.x + threadIdx.x;
    int stride = gridDim.x * blockDim.x;
    for (int e = gid; e < E; e += stride) {
        float4 d = ed4[e];
        int t = trgA[e];
        float4 den = denom4[t];
        float4 att;
        att.x = lrelu_exp(d.x + m0, smax) / (den.x + 1e-16f);
        att.y = lrelu_exp(d.y + m1, smax) / (den.y + 1e-16f);
        att.z = lrelu_exp(d.z + m2, smax) / (den.z + 1e-16f);
        att.w = lrelu_exp(d.w + m3, smax) / (den.w + 1e-16f);
        nt_store4(att, &attOut4[e]);
    }
}

extern "C" void kernel_launch(void* const* d_in, const int* in_sizes, int n_in,
                              void* d_out, int out_size, void* d_ws, size_t ws_size,
                              hipStream_t stream)
{
    const float* nodes  = (const float*)d_in[0];   // [N,4,16]
    const int*   ei     = (const int*)d_in[1];     // [2,E]
    const float* w_edge = (const float*)d_in[2];   // [1,4,16]
    const float* w_dist = (const float*)d_in[3];   // [1,4,16]

    const int N = in_sizes[0] / 64;
    const int E = in_sizes[1] / 2;
    const int* trgA = ei;          // edge_index[0]
    const int* srcA = ei + E;      // edge_index[1]

    float*  out_att   = (float*)d_out;                               // [E*4]
    float4* out_fsrc4 = (float4*)((float*)d_out + (size_t)E * 4);    // [E*16] float4

    // workspace layout (all 16B-aligned)
    float*    ed     = (float*)d_ws;                        // E*4 floats
    float*    denomR = ed + (size_t)E * 4;                  // NREP*N*4 floats
    float*    denom  = denomR + (size_t)NREP * N * 4;       // N*4 floats
    double*   gsum   = (double*)(denom + (size_t)N * 4);    // 4 doubles
    unsigned* gminu  = (unsigned*)(gsum + 4);               // 4 uints
    float*    consts = (float*)(gminu + 4);                 // mean[4], smax

    gnd_init<<<1024, 256, 0, stream>>>(denomR, gsum, gminu, NREP * N * 4);

    gnd_pass1<<<2048, 256, 0, stream>>>((const float4*)nodes, trgA, srcA,
                                        (const float4*)w_edge, (const float4*)w_dist,
                                        out_fsrc4, ed, gsum, gminu, E);
    gnd_finalize<<<1, 64, 0, stream>>>(gsum, gminu, consts, E);

    gnd_pass2<<<2048, 256, 0, stream>>>(ed, trgA, consts, denomR, E * 4, N * 4);
    gnd_collapse<<<512, 256, 0, stream>>>((const float4*)denomR, (float4*)denom, N);
    gnd_pass3<<<2048, 256, 0, stream>>>((const float4*)ed, trgA, consts,
                                        (const float4*)denom, (float4*)out_att, E);
}

// Round 6
// 278.322 us; speedup vs baseline: 1.0214x; 1.0214x over previous
//
#include <hip/hip_runtime.h>

// GND_61873298866219 — graph attention distance kernel
// Outputs (concat): attentions [E,4] floats, then f_src [E,4,16] floats.

typedef float fvec4 __attribute__((ext_vector_type(4)));  // native vec for nontemporal builtins

static __device__ __forceinline__ void nt_store4(const float4& v, float4* p) {
    fvec4 nv = { v.x, v.y, v.z, v.w };
    __builtin_nontemporal_store(nv, (fvec4*)p);
}

static __device__ __forceinline__ unsigned fmap_ord(float x) {
    // order-preserving float -> uint map (for atomicMin)
    unsigned u = __float_as_uint(x);
    return (u >> 31) ? ~u : (u | 0x80000000u);
}

__global__ void gnd_init(float* __restrict__ denom, double* __restrict__ gsum,
                         unsigned* __restrict__ gminu, int n)  // n = N*4
{
    int i = blockIdx.x * blockDim.x + threadIdx.x;
    int stride = gridDim.x * blockDim.x;
    for (int j = i; j < n; j += stride) denom[j] = 0.0f;
    if (blockIdx.x == 0 && threadIdx.x < 4) {
        gsum[threadIdx.x] = 0.0;
        gminu[threadIdx.x] = 0xFFFFFFFFu;
    }
}

#define B1 8  // edge-groups batched per thread iteration (16 gathers in flight)

__global__ __launch_bounds__(256, 4) void gnd_pass1(
    const float4* __restrict__ nodes4,     // [N*16] float4 (N nodes x 64 floats)
    const int* __restrict__ trgA,          // [E]
    const int* __restrict__ srcA,          // [E]
    const float4* __restrict__ w_edge4,    // [16]
    const float4* __restrict__ w_dist4,    // [16]
    float4* __restrict__ out_fsrc4,        // [E*16]
    float* __restrict__ ed,                // [E*4]
    double* __restrict__ gsum,             // [4]
    unsigned* __restrict__ gminu,          // [4]
    int E)
{
    const int lane = threadIdx.x & 63;
    const int q = lane & 15;               // float4 index within node (0..15)
    const int h = (lane >> 2) & 3;         // head for this lane's float4
    const float4 wE = w_edge4[q];
    const float4 wD = w_dist4[q];

    double sumAcc = 0.0;
    float  minAcc = 3.4e38f;

    const int gid  = blockIdx.x * blockDim.x + threadIdx.x;
    const int grp0 = gid >> 4;                          // edge-group id
    const int ngrp = (gridDim.x * blockDim.x) >> 4;     // total groups

    for (int base = grp0; base < E; base += B1 * ngrp) {
        int   tA[B1], sA[B1];
        float4 fsA[B1], ftA[B1];
        #pragma unroll
        for (int k = 0; k < B1; ++k) {
            int e = base + k * ngrp;
            if (e < E) { tA[k] = trgA[e]; sA[k] = srcA[e]; }
        }
        #pragma unroll
        for (int k = 0; k < B1; ++k) {
            int e = base + k * ngrp;
            if (e < E) {
                fsA[k] = nodes4[sA[k] * 16 + q];
                ftA[k] = nodes4[tA[k] * 16 + q];
            }
        }
        #pragma unroll
        for (int k = 0; k < B1; ++k) {
            int e = base + k * ngrp;
            if (e >= E) break;
            float4 fs = fsA[k], ft = ftA[k];
            nt_store4(fs, &out_fsrc4[(size_t)e * 16 + q]);
            float ax = (ft.x - fs.x) * wE.x;
            float ay = (ft.y - fs.y) * wE.y;
            float az = (ft.z - fs.z) * wE.z;
            float aw = (ft.w - fs.w) * wE.w;
            float v = ax * ax * wD.x + ay * ay * wD.y + az * az * wD.z + aw * aw * wD.w;
            // reduce the 4 lanes of one head (adjacent lanes, uniform e per group)
            v += __shfl_xor(v, 1);
            v += __shfl_xor(v, 2);
            if ((lane & 3) == 0) {
                __builtin_nontemporal_store(v, &ed[(size_t)e * 4 + h]);
                sumAcc += (double)v;
                minAcc = fminf(minAcc, v);
            }
        }
    }
    // wave-level: combine the 4 contributing 16-lane groups (same h at lane^16, lane^32)
    sumAcc += __shfl_xor(sumAcc, 16);
    sumAcc += __shfl_xor(sumAcc, 32);
    minAcc = fminf(minAcc, __shfl_xor(minAcc, 16));
    minAcc = fminf(minAcc, __shfl_xor(minAcc, 32));

    __shared__ double sSum[4][4];  // [wave][head]
    __shared__ float  sMin[4][4];
    int wv = threadIdx.x >> 6;
    if (lane < 16 && (lane & 3) == 0) {
        sSum[wv][h] = sumAcc;
        sMin[wv][h] = minAcc;
    }
    __syncthreads();
    if (threadIdx.x < 4) {
        int hh = threadIdx.x;
        double s = sSum[0][hh] + sSum[1][hh] + sSum[2][hh] + sSum[3][hh];
        float  m = fminf(fminf(sMin[0][hh], sMin[1][hh]),
                         fminf(sMin[2][hh], sMin[3][hh]));
        atomicAdd(&gsum[hh], s);
        atomicMin(&gminu[hh], fmap_ord(m));
    }
}

__global__ void gnd_finalize(const double* __restrict__ gsum,
                             const unsigned* __restrict__ gminu,
                             float* __restrict__ consts, int E)
{
    if (threadIdx.x == 0 && blockIdx.x == 0) {
        float smax = -3.4e38f;
        for (int hh = 0; hh < 4; ++hh) {
            float mean = (float)(gsum[hh] / (double)E);
            unsigned m = gminu[hh];
            unsigned bits = (m >> 31) ? (m ^ 0x80000000u) : ~m;
            float mn = __uint_as_float(bits);
            float x = mn + mean;
            float lr = (x >= 0.f) ? x : 0.2f * x;
            smax = fmaxf(smax, -lr);
            consts[hh] = mean;
        }
        consts[4] = smax;
    }
}

static __device__ __forceinline__ float lrelu_exp(float x, float smax) {
    float lr = (x >= 0.f) ? x : 0.2f * x;
    return expf(-lr - smax);
}

static __device__ __forceinline__ float head_mean(float m0, float m1, float m2, float m3, int hh) {
    float a = (hh & 1) ? m1 : m0;
    float b = (hh & 1) ? m3 : m2;
    return (hh & 2) ? b : a;
}

// per-(edge,head) mapping: adjacent lanes -> same edge, 4 consecutive denom
// addresses (one 16B sector per edge) — atomic line-coalescing.
__global__ __launch_bounds__(256) void gnd_pass2(
    const float* __restrict__ ed,          // [E*4]
    const int* __restrict__ trgA,
    const float* __restrict__ consts,
    float* __restrict__ denom,             // [N*4], pre-zeroed
    int total)                             // E*4
{
    const float m0 = consts[0], m1 = consts[1], m2 = consts[2], m3 = consts[3];
    const float smax = consts[4];
    int gid = blockIdx.x * blockDim.x + threadIdx.x;
    int stride = gridDim.x * blockDim.x;
    for (int i = gid; i < total; i += stride) {
        int e = i >> 2, hh = i & 3;
        float x = ed[i] + head_mean(m0, m1, m2, m3, hh);
        unsafeAtomicAdd(&denom[trgA[e] * 4 + hh], lrelu_exp(x, smax));
    }
}

__global__ __launch_bounds__(256) void gnd_pass3(
    const float4* __restrict__ ed4,
    const int* __restrict__ trgA,
    const float* __restrict__ consts,
    const float4* __restrict__ denom4,     // [N]
    float4* __restrict__ attOut4,          // [E]
    int E)
{
    const float m0 = consts[0], m1 = consts[1], m2 = consts[2], m3 = consts[3];
    const float smax = consts[4];
    int gid = blockIdx.x * blockDim.x + threadIdx.x;
    int stride = gridDim.x * blockDim.x;
    for (int e = gid; e < E; e += stride) {
        float4 d = ed4[e];
        int t = trgA[e];
        float4 den = denom4[t];
        float4 att;
        att.x = lrelu_exp(d.x + m0, smax) / (den.x + 1e-16f);
        att.y = lrelu_exp(d.y + m1, smax) / (den.y + 1e-16f);
        att.z = lrelu_exp(d.z + m2, smax) / (den.z + 1e-16f);
        att.w = lrelu_exp(d.w + m3, smax) / (den.w + 1e-16f);
        nt_store4(att, &attOut4[e]);
    }
}

extern "C" void kernel_launch(void* const* d_in, const int* in_sizes, int n_in,
                              void* d_out, int out_size, void* d_ws, size_t ws_size,
                              hipStream_t stream)
{
    const float* nodes  = (const float*)d_in[0];   // [N,4,16]
    const int*   ei     = (const int*)d_in[1];     // [2,E]
    const float* w_edge = (const float*)d_in[2];   // [1,4,16]
    const float* w_dist = (const float*)d_in[3];   // [1,4,16]

    const int N = in_sizes[0] / 64;
    const int E = in_sizes[1] / 2;
    const int* trgA = ei;          // edge_index[0]
    const int* srcA = ei + E;      // edge_index[1]

    float*  out_att   = (float*)d_out;                               // [E*4]
    float4* out_fsrc4 = (float4*)((float*)d_out + (size_t)E * 4);    // [E*16] float4

    // workspace layout (all 16B-aligned)
    float*    ed     = (float*)d_ws;                        // E*4 floats
    float*    denom  = ed + (size_t)E * 4;                  // N*4 floats
    double*   gsum   = (double*)(denom + (size_t)N * 4);    // 4 doubles
    unsigned* gminu  = (unsigned*)(gsum + 4);               // 4 uints
    float*    consts = (float*)(gminu + 4);                 // mean[4], smax

    gnd_init<<<256, 256, 0, stream>>>(denom, gsum, gminu, N * 4);

    gnd_pass1<<<2048, 256, 0, stream>>>((const float4*)nodes, trgA, srcA,
                                        (const float4*)w_edge, (const float4*)w_dist,
                                        out_fsrc4, ed, gsum, gminu, E);
    gnd_finalize<<<1, 64, 0, stream>>>(gsum, gminu, consts, E);

    gnd_pass2<<<2048, 256, 0, stream>>>(ed, trgA, consts, denom, E * 4);
    gnd_pass3<<<2048, 256, 0, stream>>>((const float4*)ed, trgA, consts,
                                        (const float4*)denom, (float4*)out_att, E);
}

// Round 8
// 278.270 us; speedup vs baseline: 1.0216x; 1.0002x over previous
//
#include <hip/hip_runtime.h>
#include <hip/hip_fp16.h>

// GND_61873298866219 — graph attention distance kernel
// Outputs (concat): attentions [E,4] floats, then f_src [E,4,16] floats.

typedef float fvec4 __attribute__((ext_vector_type(4)));  // native vec for nontemporal builtins

static __device__ __forceinline__ void nt_store4(const float4& v, float4* p) {
    fvec4 nv = { v.x, v.y, v.z, v.w };
    __builtin_nontemporal_store(nv, (fvec4*)p);
}

static __device__ __forceinline__ unsigned fmap_ord(float x) {
    // order-preserving float -> uint map (for atomicMin)
    unsigned u = __float_as_uint(x);
    return (u >> 31) ? ~u : (u | 0x80000000u);
}

__global__ void gnd_init(unsigned* __restrict__ denomU, double* __restrict__ gsum,
                         unsigned* __restrict__ gminu, int n)  // n = N*2 (uint words of half denom)
{
    int i = blockIdx.x * blockDim.x + threadIdx.x;
    int stride = gridDim.x * blockDim.x;
    for (int j = i; j < n; j += stride) denomU[j] = 0u;
    if (blockIdx.x == 0 && threadIdx.x < 4) {
        gsum[threadIdx.x] = 0.0;
        gminu[threadIdx.x] = 0xFFFFFFFFu;
    }
}

#define B1 4  // edge-groups batched per thread iteration (8 gathers in flight)

__global__ __launch_bounds__(256, 4) void gnd_pass1(
    const float4* __restrict__ nodes4,     // [N*16] float4 (N nodes x 64 floats)
    const int* __restrict__ trgA,          // [E]
    const int* __restrict__ srcA,          // [E]
    const float4* __restrict__ w_edge4,    // [16]
    const float4* __restrict__ w_dist4,    // [16]
    float4* __restrict__ out_fsrc4,        // [E*16]
    float* __restrict__ ed,                // [E*4]
    double* __restrict__ gsum,             // [4]
    unsigned* __restrict__ gminu,          // [4]
    int E)
{
    const int lane = threadIdx.x & 63;
    const int q = lane & 15;               // float4 index within node (0..15)
    const int h = (lane >> 2) & 3;         // head for this lane's float4
    const float4 wE = w_edge4[q];
    const float4 wD = w_dist4[q];

    double sumAcc = 0.0;
    float  minAcc = 3.4e38f;

    const int gid  = blockIdx.x * blockDim.x + threadIdx.x;
    const int grp0 = gid >> 4;                          // edge-group id
    const int ngrp = (gridDim.x * blockDim.x) >> 4;     // total groups

    for (int base = grp0; base < E; base += B1 * ngrp) {
        int   tA[B1], sA[B1];
        float4 fsA[B1], ftA[B1];
        #pragma unroll
        for (int k = 0; k < B1; ++k) {
            int e = base + k * ngrp;
            if (e < E) { tA[k] = trgA[e]; sA[k] = srcA[e]; }
        }
        #pragma unroll
        for (int k = 0; k < B1; ++k) {
            int e = base + k * ngrp;
            if (e < E) {
                fsA[k] = nodes4[sA[k] * 16 + q];
                ftA[k] = nodes4[tA[k] * 16 + q];
            }
        }
        #pragma unroll
        for (int k = 0; k < B1; ++k) {
            int e = base + k * ngrp;
            if (e >= E) break;
            float4 fs = fsA[k], ft = ftA[k];
            nt_store4(fs, &out_fsrc4[(size_t)e * 16 + q]);
            float ax = (ft.x - fs.x) * wE.x;
            float ay = (ft.y - fs.y) * wE.y;
            float az = (ft.z - fs.z) * wE.z;
            float aw = (ft.w - fs.w) * wE.w;
            float v = ax * ax * wD.x + ay * ay * wD.y + az * az * wD.z + aw * aw * wD.w;
            // reduce the 4 lanes of one head (adjacent lanes, uniform e per group)
            v += __shfl_xor(v, 1);
            v += __shfl_xor(v, 2);
            if ((lane & 3) == 0) {
                __builtin_nontemporal_store(v, &ed[(size_t)e * 4 + h]);
                sumAcc += (double)v;
                minAcc = fminf(minAcc, v);
            }
        }
    }
    // wave-level: combine the 4 contributing 16-lane groups (same h at lane^16, lane^32)
    sumAcc += __shfl_xor(sumAcc, 16);
    sumAcc += __shfl_xor(sumAcc, 32);
    minAcc = fminf(minAcc, __shfl_xor(minAcc, 16));
    minAcc = fminf(minAcc, __shfl_xor(minAcc, 32));

    __shared__ double sSum[4][4];  // [wave][head]
    __shared__ float  sMin[4][4];
    int wv = threadIdx.x >> 6;
    if (lane < 16 && (lane & 3) == 0) {
        sSum[wv][h] = sumAcc;
        sMin[wv][h] = minAcc;
    }
    __syncthreads();
    if (threadIdx.x < 4) {
        int hh = threadIdx.x;
        double s = sSum[0][hh] + sSum[1][hh] + sSum[2][hh] + sSum[3][hh];
        float  m = fminf(fminf(sMin[0][hh], sMin[1][hh]),
                         fminf(sMin[2][hh], sMin[3][hh]));
        atomicAdd(&gsum[hh], s);
        atomicMin(&gminu[hh], fmap_ord(m));
    }
}

__global__ void gnd_finalize(const double* __restrict__ gsum,
                             const unsigned* __restrict__ gminu,
                             float* __restrict__ consts, int E)
{
    if (threadIdx.x == 0 && blockIdx.x == 0) {
        float smax = -3.4e38f;
        for (int hh = 0; hh < 4; ++hh) {
            float mean = (float)(gsum[hh] / (double)E);
            unsigned m = gminu[hh];
            unsigned bits = (m >> 31) ? (m ^ 0x80000000u) : ~m;
            float mn = __uint_as_float(bits);
            float x = mn + mean;
            float lr = (x >= 0.f) ? x : 0.2f * x;
            smax = fmaxf(smax, -lr);
            consts[hh] = mean;
        }
        consts[4] = smax;
    }
}

static __device__ __forceinline__ float lrelu_exp(float x, float smax) {
    float lr = (x >= 0.f) ? x : 0.2f * x;
    return expf(-lr - smax);
}

// per-(edge,head-pair) mapping: 2 adjacent lanes per edge; each lane does ONE
// packed f16x2 atomic (native global_atomic_pk_add_f16) — halves atomic ops.
__global__ __launch_bounds__(256) void gnd_pass2(
    const float2* __restrict__ ed2,        // [E*2] (head pairs)
    const int* __restrict__ trgA,
    const float* __restrict__ consts,
    __half2* __restrict__ denomH2,         // [N*2], pre-zeroed
    int total2)                            // E*2
{
    const float m0 = consts[0], m1 = consts[1], m2 = consts[2], m3 = consts[3];
    const float smax = consts[4];
    int gid = blockIdx.x * blockDim.x + threadIdx.x;
    int stride = gridDim.x * blockDim.x;
    for (int i = gid; i < total2; i += stride) {
        int e = i >> 1, hp = i & 1;
        float2 d = ed2[i];
        float ma = hp ? m2 : m0;
        float mb = hp ? m3 : m1;
        float ea = lrelu_exp(d.x + ma, smax);
        float eb = lrelu_exp(d.y + mb, smax);
        __half2 hv = __floats2half2_rn(ea, eb);
        unsafeAtomicAdd(&denomH2[(size_t)trgA[e] * 2 + hp], hv);
    }
}

__global__ __launch_bounds__(256) void gnd_pass3(
    const float4* __restrict__ ed4,
    const int* __restrict__ trgA,
    const float* __restrict__ consts,
    const uint2* __restrict__ denomU2,     // [N] (4 halfs per node)
    float4* __restrict__ attOut4,          // [E]
    int E)
{
    const float m0 = consts[0], m1 = consts[1], m2 = consts[2], m3 = consts[3];
    const float smax = consts[4];
    int gid = blockIdx.x * blockDim.x + threadIdx.x;
    int stride = gridDim.x * blockDim.x;
    for (int e = gid; e < E; e += stride) {
        float4 d = ed4[e];
        int t = trgA[e];
        uint2 dv = denomU2[t];
        __half2 h01 = *reinterpret_cast<__half2*>(&dv.x);
        __half2 h23 = *reinterpret_cast<__half2*>(&dv.y);
        float den0 = __low2float(h01), den1 = __high2float(h01);
        float den2 = __low2float(h23), den3 = __high2float(h23);
        float4 att;
        att.x = lrelu_exp(d.x + m0, smax) / (den0 + 1e-16f);
        att.y = lrelu_exp(d.y + m1, smax) / (den1 + 1e-16f);
        att.z = lrelu_exp(d.z + m2, smax) / (den2 + 1e-16f);
        att.w = lrelu_exp(d.w + m3, smax) / (den3 + 1e-16f);
        nt_store4(att, &attOut4[e]);
    }
}

extern "C" void kernel_launch(void* const* d_in, const int* in_sizes, int n_in,
                              void* d_out, int out_size, void* d_ws, size_t ws_size,
                              hipStream_t stream)
{
    const float* nodes  = (const float*)d_in[0];   // [N,4,16]
    const int*   ei     = (const int*)d_in[1];     // [2,E]
    const float* w_edge = (const float*)d_in[2];   // [1,4,16]
    const float* w_dist = (const float*)d_in[3];   // [1,4,16]

    const int N = in_sizes[0] / 64;
    const int E = in_sizes[1] / 2;
    const int* trgA = ei;          // edge_index[0]
    const int* srcA = ei + E;      // edge_index[1]

    float*  out_att   = (float*)d_out;                               // [E*4]
    float4* out_fsrc4 = (float4*)((float*)d_out + (size_t)E * 4);    // [E*16] float4

    // workspace layout (all 16B-aligned)
    float*    ed     = (float*)d_ws;                        // E*4 floats
    unsigned* denomU = (unsigned*)(ed + (size_t)E * 4);     // N*2 uints (= N*4 halfs)
    double*   gsum   = (double*)(denomU + (size_t)N * 2);   // 4 doubles
    unsigned* gminu  = (unsigned*)(gsum + 4);               // 4 uints
    float*    consts = (float*)(gminu + 4);                 // mean[4], smax

    gnd_init<<<256, 256, 0, stream>>>(denomU, gsum, gminu, N * 2);

    gnd_pass1<<<2048, 256, 0, stream>>>((const float4*)nodes, trgA, srcA,
                                        (const float4*)w_edge, (const float4*)w_dist,
                                        out_fsrc4, ed, gsum, gminu, E);
    gnd_finalize<<<1, 64, 0, stream>>>(gsum, gminu, consts, E);

    gnd_pass2<<<2048, 256, 0, stream>>>((const float2*)ed, trgA, consts,
                                        (__half2*)denomU, E * 2);
    gnd_pass3<<<2048, 256, 0, stream>>>((const float4*)ed, trgA, consts,
                                        (const uint2*)denomU, (float4*)out_att, E);
}